// Round 1
// baseline (409.791 us; speedup 1.0000x reference)
//
#include <hip/hip_runtime.h>

#define N_    8192
#define FIN_  256
#define NHID_ 128
#define E_    524288
#define KTOP  32
#define MAXM  512   // max edges per row; E/N=64 mean, multinomial max ~110 — 512 is ultra-safe

// ---------------- GEMM: h = relu(x @ W1 + b1) ----------------
__global__ __launch_bounds__(256) void k_gemm(const float* __restrict__ x,
                                              const float* __restrict__ W1,
                                              const float* __restrict__ b1,
                                              float* __restrict__ h) {
    __shared__ float xs[8][FIN_];
    int t = threadIdx.x;
    int row0 = blockIdx.x * 8;
    for (int i = t; i < 8 * FIN_; i += 256)
        xs[i >> 8][i & 255] = x[(size_t)row0 * FIN_ + i];
    __syncthreads();
    int j  = t & 127;          // output column
    int rb = (t >> 7) * 4;     // 4 rows per thread
    float acc0 = 0.f, acc1 = 0.f, acc2 = 0.f, acc3 = 0.f;
#pragma unroll 8
    for (int k = 0; k < FIN_; ++k) {
        float w = W1[k * NHID_ + j];   // coalesced, L2-resident (W1 = 128 KB)
        acc0 += xs[rb + 0][k] * w;
        acc1 += xs[rb + 1][k] * w;
        acc2 += xs[rb + 2][k] * w;
        acc3 += xs[rb + 3][k] * w;
    }
    float bj = b1[j];
    float v0 = acc0 + bj, v1 = acc1 + bj, v2 = acc2 + bj, v3 = acc3 + bj;
    v0 = v0 > 0.f ? v0 : 0.f;
    v1 = v1 > 0.f ? v1 : 0.f;
    v2 = v2 > 0.f ? v2 : 0.f;
    v3 = v3 > 0.f ? v3 : 0.f;
    h[(size_t)(row0 + rb + 0) * NHID_ + j] = v0;
    h[(size_t)(row0 + rb + 1) * NHID_ + j] = v1;
    h[(size_t)(row0 + rb + 2) * NHID_ + j] = v2;
    h[(size_t)(row0 + rb + 3) * NHID_ + j] = v3;
}

// ---------------- per-node scalars a = h.We1, b = h.We2 ----------------
__global__ __launch_bounds__(256) void k_ab(const float* __restrict__ h,
                                            const float* __restrict__ We,
                                            float* __restrict__ a,
                                            float* __restrict__ b) {
    int t = threadIdx.x;
    int wave = t >> 6, lane = t & 63;
    int node = blockIdx.x * 4 + wave;   // one wave per node
    const float* hr = h + (size_t)node * NHID_;
    float h0 = hr[lane], h1 = hr[lane + 64];
    float p = h0 * We[lane]       + h1 * We[lane + 64];
    float q = h0 * We[128 + lane] + h1 * We[192 + lane];
    for (int o = 32; o > 0; o >>= 1) { p += __shfl_down(p, o); q += __shfl_down(q, o); }
    if (lane == 0) { a[node] = p; b[node] = q; }
}

// ---------------- count edges per row ----------------
__global__ __launch_bounds__(256) void k_count(const int* __restrict__ ei,
                                               int* __restrict__ counts) {
    int e = blockIdx.x * 256 + threadIdx.x;
    atomicAdd(&counts[ei[e]], 1);
}

// ---------------- exclusive scan over N counts (single block) ----------------
__global__ __launch_bounds__(256) void k_scan(const int* __restrict__ counts,
                                              int* __restrict__ starts,
                                              int* __restrict__ cursor) {
    __shared__ int part[256];
    int t = threadIdx.x;
    int base = t * (N_ / 256);
    int local[N_ / 256];
    int sum = 0;
    for (int i = 0; i < N_ / 256; ++i) { local[i] = sum; sum += counts[base + i]; }
    part[t] = sum;
    __syncthreads();
    if (t == 0) {
        int acc = 0;
        for (int i = 0; i < 256; ++i) { int v = part[i]; part[i] = acc; acc += v; }
    }
    __syncthreads();
    int off = part[t];
    for (int i = 0; i < N_ / 256; ++i) {
        int s = off + local[i];
        starts[base + i] = s;
        cursor[base + i] = s;
    }
}

// ---------------- bucket edges by row; z = a[row] + b[col] + be ----------------
__global__ __launch_bounds__(256) void k_scatter(const int* __restrict__ ei,
                                                 const float* __restrict__ a,
                                                 const float* __restrict__ b,
                                                 const float* __restrict__ be,
                                                 int* __restrict__ cursor,
                                                 int* __restrict__ ecol,
                                                 float* __restrict__ ez) {
    int e = blockIdx.x * 256 + threadIdx.x;
    int r = ei[e];
    int c = ei[E_ + e];
    int pos = atomicAdd(&cursor[r], 1);
    ecol[pos] = c;
    ez[pos] = a[r] + b[c] + be[0];
}

// ---------------- per-row sparsemax + topK threshold + dense row write ----------------
__global__ __launch_bounds__(256) void k_rows(const int* __restrict__ counts,
                                              const int* __restrict__ starts,
                                              const int* __restrict__ ecol,
                                              const float* __restrict__ ez,
                                              float* __restrict__ adj) {
    __shared__ float zs[MAXM];
    __shared__ int   cols[MAXM];
    __shared__ float srt[MAXM];
    __shared__ unsigned char dupf[MAXM];
    __shared__ float s_tau, s_thresh;

    int r = blockIdx.x;
    int t = threadIdx.x;
    int m = counts[r];
    if (m > MAXM) m = MAXM;          // never expected; avoids LDS OOB
    int base = starts[r];

    // phase 0: load bucket into LDS; zero the dense output row
    for (int i = t; i < m; i += 256) {
        zs[i]   = ez[base + i];
        cols[i] = ecol[base + i];
    }
    float* row = adj + (size_t)r * N_;
    float4* row4 = (float4*)row;
    float4 z4 = make_float4(0.f, 0.f, 0.f, 0.f);
    for (int i = t; i < N_ / 4; i += 256) row4[i] = z4;
    __syncthreads();                  // drains vmcnt: zeros committed, LDS visible
    if (m == 0) return;               // empty row stays all-zero (uniform branch)

    // phase 1: descending rank (ties by bucket index) -> sorted array; dup flags by col
    for (int i = t; i < m; i += 256) {
        float zi = zs[i];
        int rank = 0;
        for (int jj = 0; jj < m; ++jj) {
            float zj = zs[jj];
            rank += (zj > zi) || (zj == zi && jj < i);
        }
        srt[rank] = zi;
        int ci = cols[i];
        bool dup = false;
        for (int jj = 0; jj < i; ++jj)
            if (cols[jj] == ci) { dup = true; break; }
        dupf[i] = dup ? 1 : 0;
    }
    __syncthreads();

    // phase 2: sparsemax support + tau (sequential; m <= ~120)
    if (t == 0) {
        float c = 0.f;
        int kmax = 1;
        float csk = srt[0];
        for (int jj = 0; jj < m; ++jj) {
            c += srt[jj];
            if (1.0f + (float)(jj + 1) * srt[jj] > c) { kmax = jj + 1; csk = c; }
        }
        s_tau = (csk - 1.0f) / (float)kmax;
        s_thresh = 0.f;
    }
    __syncthreads();
    float tau = s_tau;

    // phase 3: K-th largest among UNIQUE cols (duplicates collapse in the dense adj)
    for (int i = t; i < m; i += 256) {
        if (dupf[i]) continue;
        float zi = zs[i];
        int rank = 0;
        for (int jj = 0; jj < m; ++jj) {
            if (dupf[jj] || jj == i) continue;
            float zj = zs[jj];
            rank += (zj > zi) || (zj == zi && jj < i);
        }
        if (rank == KTOP - 1) {       // exactly one element (strict total order)
            float s = zi - tau;
            s_thresh = s > 0.f ? s : 0.f;
        }
    }
    __syncthreads();
    float thresh = s_thresh;

    // phase 4: scatter kept scores (dups write identical values — benign)
    for (int i = t; i < m; i += 256) {
        float s = zs[i] - tau;
        if (s > 0.f && s >= thresh) row[cols[i]] = s;
    }
}

extern "C" void kernel_launch(void* const* d_in, const int* in_sizes, int n_in,
                              void* d_out, int out_size, void* d_ws, size_t ws_size,
                              hipStream_t stream) {
    const float* x  = (const float*)d_in[0];
    const int*   ei = (const int*)d_in[1];
    const float* W1 = (const float*)d_in[2];
    const float* b1 = (const float*)d_in[3];
    const float* We = (const float*)d_in[4];
    const float* be = (const float*)d_in[5];

    float* h_out   = (float*)d_out;                 // (N, NHID)
    float* adj_out = h_out + (size_t)N_ * NHID_;    // (N, N)

    float* a      = (float*)d_ws;                   // N
    float* b      = a + N_;                         // N
    int*   counts = (int*)(b + N_);                 // N
    int*   starts = counts + N_;                    // N
    int*   cursor = starts + N_;                    // N
    int*   ecol   = cursor + N_;                    // E
    float* ez     = (float*)(ecol + E_);            // E

    hipMemsetAsync(counts, 0, N_ * sizeof(int), stream);
    k_gemm   <<<N_ / 8, 256, 0, stream>>>(x, W1, b1, h_out);
    k_ab     <<<N_ / 4, 256, 0, stream>>>(h_out, We, a, b);
    k_count  <<<E_ / 256, 256, 0, stream>>>(ei, counts);
    k_scan   <<<1, 256, 0, stream>>>(counts, starts, cursor);
    k_scatter<<<E_ / 256, 256, 0, stream>>>(ei, a, b, be, cursor, ecol, ez);
    k_rows   <<<N_, 256, 0, stream>>>(counts, starts, ecol, ez, adj_out);
}